// Round 6
// baseline (164.050 us; speedup 1.0000x reference)
//
#include <hip/hip_runtime.h>

// D2Q9 MRT (Gram-Schmidt) LBM on 1024x1024, 4 iterations.
// Chain (S C)^4 with each kernel = pull-stream + collide + own-cell write:
//   k1 : AoS input (LDS row staging for the 9-way gather) -> SoA
//   k2 : SoA -> SoA   (pull via shifted vector loads, aligned f4 stores)
//   k3 : SoA -> SoA
//   k4 : SoA -> AoS   (pull reads; AoS write via register->LDS->coalesced f4)
// Pull: f_q(x,y) = src_q((x-ex_q)&1023, (y-ey_q)&1023). Own-cell writes are
// always aligned float4 (SoA) or coalesced (k1 scalar / k4 via LDS).

#define NXD 1024
#define NYD 1024
#define NCELL (NXD * NYD)
#define ROWF (NYD * 9)   // floats per AoS row = 9216

// TAU=0.6, GX=0 (folds away exactly), GY=-1e-4
constexpr float INV_TAU = (float)(1.0 / 0.6);
constexpr float TGY     = (float)(0.6 * -1e-4);   // TAU*GY

__device__ __forceinline__ void collide1(
    float f0, float f1, float f2, float f3, float f4,
    float f5, float f6, float f7, float f8,
    float w0, float w1, float w2, float w3, float w4, float w5, float w6,
    float& o0, float& o1, float& o2, float& o3, float& o4,
    float& o5, float& o6, float& o7, float& o8)
{
    const float rho = f0 + f1 + f2 + f3 + f4 + f5 + f6 + f7 + f8;
    const float jx0 = f1 - f3 + f5 - f6 - f7 + f8;
    const float jy0 = f2 - f4 + f5 + f6 - f7 - f8;
    const float vx = jx0 / rho;
    const float vy = jy0 / rho;
    const float uy = vy + TGY * rho;           // ux == vx (GX=0)
    const float jx = rho * vx;
    const float jy = rho * uy;
    const float j2 = jx * jx + jy * jy;

    const float ax = f1 + f2 + f3 + f4;
    const float dg = f5 + f6 + f7 + f8;
    const float m3 = -4.f * f0 - ax + 2.f * dg;
    const float m4 =  4.f * f0 - 2.f * ax + dg;
    const float m5 = -2.f * f1 + 2.f * f3 + f5 - f6 - f7 + f8;
    const float m6 = -2.f * f2 + 2.f * f4 + f5 + f6 - f7 - f8;
    const float m7 = f1 - f2 + f3 - f4;
    const float m8 = f5 - f6 + f7 - f8;

    const float me3 = w0 * rho + w1 * j2;
    const float me4 = w2 * rho - w3 * j2;
    const float me5 = w4 * jx;
    const float me6 = w4 * jy;
    const float me7 = w5 * (jx * jx - jy * jy);
    const float me8 = w6 * (jx * jy);

    const float mp1 = jx0 - INV_TAU * (jx0 - jx);
    const float mp2 = jy0 - INV_TAU * (jy0 - jy);
    const float mp3 = m3  - INV_TAU * (m3 - me3);
    const float mp4 = m4  - INV_TAU * (m4 - me4);
    const float mp5 = m5  - INV_TAU * (m5 - me5);
    const float mp6 = m6  - INV_TAU * (m6 - me6);
    const float mp7 = m7  - INV_TAU * (m7 - me7);
    const float mp8 = m8  - INV_TAU * (m8 - me8);

    const float s0 = rho * (1.f / 9.f);
    const float s1 = mp1 * (1.f / 6.f);
    const float s2 = mp2 * (1.f / 6.f);
    const float s3 = mp3 * (1.f / 36.f);
    const float s4 = mp4 * (1.f / 36.f);
    const float s5 = mp5 * (1.f / 12.f);
    const float s6 = mp6 * (1.f / 12.f);
    const float s7 = mp7 * 0.25f;
    const float s8 = mp8 * 0.25f;

    const float h0 = s0 - s3 - 2.f * s4;
    const float g0 = s0 + 2.f * s3 + s4;

    o0 = s0 - 4.f * s3 + 4.f * s4;
    o1 = h0 + s1 - 2.f * s5 + s7;
    o2 = h0 + s2 - 2.f * s6 - s7;
    o3 = h0 - s1 + 2.f * s5 + s7;
    o4 = h0 - s2 + 2.f * s6 - s7;
    o5 = g0 + s1 + s2 + s5 + s6 + s8;
    o6 = g0 - s1 + s2 - s5 + s6 - s8;
    o7 = g0 - s1 - s2 - s5 - s6 + s8;
    o8 = g0 + s1 - s2 + s5 - s6 - s8;
}

// collide 4 cells held as 9 float4 fragments (fully unrolled -> stays in regs)
__device__ __forceinline__ void collide4(const float4 (&F)[9], float4 (&O)[9],
                                         const float (&w)[7]) {
    #pragma unroll
    for (int j = 0; j < 4; ++j) {
        float f[9], o[9];
        #pragma unroll
        for (int q = 0; q < 9; ++q)
            f[q] = ((const float*)&F[q])[j];
        collide1(f[0], f[1], f[2], f[3], f[4], f[5], f[6], f[7], f[8],
                 w[0], w[1], w[2], w[3], w[4], w[5], w[6],
                 o[0], o[1], o[2], o[3], o[4], o[5], o[6], o[7], o[8]);
        #pragma unroll
        for (int q = 0; q < 9; ++q)
            ((float*)&O[q])[j] = o[q];
    }
}

// possibly-unaligned / row-wrapping float4 load from one SoA plane row
__device__ __forceinline__ float4 ld4s(const float* __restrict__ rowp, int yb) {
    if (yb >= 0 && yb + 3 < NYD) {
        float4 v;
        __builtin_memcpy(&v, rowp + yb, sizeof(float4));  // align-4 dwordx4
        return v;
    }
    float4 v;   // only lanes at row edges (2 per 256) take this path
    v.x = rowp[(yb + 0) & (NYD - 1)];
    v.y = rowp[(yb + 1) & (NYD - 1)];
    v.z = rowp[(yb + 2) & (NYD - 1)];
    v.w = rowp[(yb + 3) & (NYD - 1)];
    return v;
}

// pull-gather the 9 float4 fragments for cells (x, y0..y0+3) from SoA src
__device__ __forceinline__ void pull_loads(const float* __restrict__ src,
                                           int x, int y0, float4 (&F)[9]) {
    const int xm = (x - 1) & (NXD - 1), xp = (x + 1) & (NXD - 1);
    const float* p0 = src + 0 * NCELL + x  * NYD;
    const float* p1 = src + 1 * NCELL + xm * NYD;
    const float* p2 = src + 2 * NCELL + x  * NYD;
    const float* p3 = src + 3 * NCELL + xp * NYD;
    const float* p4 = src + 4 * NCELL + x  * NYD;
    const float* p5 = src + 5 * NCELL + xm * NYD;
    const float* p6 = src + 6 * NCELL + xp * NYD;
    const float* p7 = src + 7 * NCELL + xp * NYD;
    const float* p8 = src + 8 * NCELL + xm * NYD;
    __builtin_memcpy(&F[0], p0 + y0, sizeof(float4));   // aligned
    __builtin_memcpy(&F[1], p1 + y0, sizeof(float4));
    __builtin_memcpy(&F[3], p3 + y0, sizeof(float4));
    F[2] = ld4s(p2, y0 - 1);
    F[5] = ld4s(p5, y0 - 1);
    F[6] = ld4s(p6, y0 - 1);
    F[4] = ld4s(p4, y0 + 1);
    F[7] = ld4s(p7, y0 + 1);
    F[8] = ld4s(p8, y0 + 1);
}

__device__ __forceinline__ void load_w(const float* __restrict__ wp,
                                       float (&w)[7]) {
    #pragma unroll
    for (int i = 0; i < 7; ++i) w[i] = wp[i];
}

// ---- k1: S1 C1, AoS input. Stage rows x-1,x,x+1 (cells y0-1..y0+256) in LDS.
__global__ __launch_bounds__(256) void k1_sc(const float* __restrict__ src,
                                             float* __restrict__ dst,
                                             const float* __restrict__ wp) {
    __shared__ float L[3][258 * 9];   // 27864 B
    const int b   = blockIdx.x;
    const int x   = b >> 2;
    const int y0  = (b & 3) << 8;
    const int tid = threadIdx.x;

    #pragma unroll
    for (int r = 0; r < 3; ++r) {
        const int srow = (x - 1 + r) & (NXD - 1);
        const float* rb = src + (size_t)srow * ROWF;
        const int base = y0 * 9 - 9;
        for (int p = tid; p < 258 * 9; p += 256) {
            int fr = base + p;
            if (fr < 0) fr += ROWF;
            else if (fr >= ROWF) fr -= ROWF;
            L[r][p] = rb[fr];
        }
    }
    __syncthreads();

    float w[7];
    load_w(wp, w);

    const int ly = tid;
    const int y  = y0 + ly;
    // pull-gather S1 from LDS; local index of global y' is y' - (y0-1)
    const float f0 = L[1][(ly + 1) * 9 + 0];
    const float f1 = L[0][(ly + 1) * 9 + 1];
    const float f2 = L[1][(ly + 0) * 9 + 2];
    const float f3 = L[2][(ly + 1) * 9 + 3];
    const float f4 = L[1][(ly + 2) * 9 + 4];
    const float f5 = L[0][(ly + 0) * 9 + 5];
    const float f6 = L[2][(ly + 0) * 9 + 6];
    const float f7 = L[2][(ly + 2) * 9 + 7];
    const float f8 = L[0][(ly + 2) * 9 + 8];

    float o0,o1,o2,o3,o4,o5,o6,o7,o8;
    collide1(f0,f1,f2,f3,f4,f5,f6,f7,f8,
             w[0],w[1],w[2],w[3],w[4],w[5],w[6],
             o0,o1,o2,o3,o4,o5,o6,o7,o8);

    const int c = x * NYD + y;   // own-cell SoA write, coalesced
    dst[0 * NCELL + c] = o0;
    dst[1 * NCELL + c] = o1;
    dst[2 * NCELL + c] = o2;
    dst[3 * NCELL + c] = o3;
    dst[4 * NCELL + c] = o4;
    dst[5 * NCELL + c] = o5;
    dst[6 * NCELL + c] = o6;
    dst[7 * NCELL + c] = o7;
    dst[8 * NCELL + c] = o8;
}

// ---- k2/k3: S C, SoA->SoA. Block = one x-row; thread = 4 cells. ----
__global__ __launch_bounds__(256) void k_sc(const float* __restrict__ src,
                                            float* __restrict__ dst,
                                            const float* __restrict__ wp) {
    const int x  = blockIdx.x;
    const int y0 = threadIdx.x << 2;

    float4 F[9];
    pull_loads(src, x, y0, F);

    float w[7];
    load_w(wp, w);

    float4 O[9];
    collide4(F, O, w);

    const int c = x * NYD + y0;   // all aligned float4, own-cell
    #pragma unroll
    for (int q = 0; q < 9; ++q)
        *(float4*)(dst + q * NCELL + c) = O[q];
}

// ---- k4: S C + AoS write. Thread's 4 cells = 36 contiguous AoS floats; ----
// ---- reshuffle through LDS (f4 writes from regs, coalesced f4 out).    ----
__global__ __launch_bounds__(256) void k_sc_aos(const float* __restrict__ src,
                                                float* __restrict__ dst,
                                                const float* __restrict__ wp) {
    __shared__ float4 T[ROWF / 4];    // 2304 float4 = 36864 B, one AoS row
    const int x   = blockIdx.x;
    const int tid = threadIdx.x;
    const int y0  = tid << 2;

    float4 F[9];
    pull_loads(src, x, y0, F);

    float w[7];
    load_w(wp, w);

    float4 O[9];
    collide4(F, O, w);

    // AoS order for the thread's 4 cells: 36 contiguous floats = 9 float4s.
    // Flat index k = j*9 + q (cell j, population q)
    float* t = (float*)(T + tid * 9);
    #pragma unroll
    for (int j = 0; j < 4; ++j) {
        #pragma unroll
        for (int q = 0; q < 9; ++q)
            t[j * 9 + q] = ((const float*)&O[q])[j];
    }
    __syncthreads();

    float4* dv = (float4*)(dst + (size_t)x * ROWF);
    #pragma unroll
    for (int it = 0; it < 9; ++it)
        dv[tid + it * 256] = T[tid + it * 256];
}

// ---- fallback: plain AoS->AoS fused stream+collide (scalar gather) ----
__global__ __launch_bounds__(256) void lbm_step_aos(const float* __restrict__ src,
                                                    float* __restrict__ dst,
                                                    const float* __restrict__ wp) {
    const int cell = blockIdx.x * 256 + threadIdx.x;
    const int x = cell >> 10;
    const int y = cell & (NYD - 1);
    const int xm = (x + NXD - 1) & (NXD - 1);
    const int xp = (x + 1) & (NXD - 1);
    const int ym = (y + NYD - 1) & (NYD - 1);
    const int yp = (y + 1) & (NYD - 1);

    const float f0 = src[(x  * NYD + y ) * 9 + 0];
    const float f1 = src[(xm * NYD + y ) * 9 + 1];
    const float f2 = src[(x  * NYD + ym) * 9 + 2];
    const float f3 = src[(xp * NYD + y ) * 9 + 3];
    const float f4 = src[(x  * NYD + yp) * 9 + 4];
    const float f5 = src[(xm * NYD + ym) * 9 + 5];
    const float f6 = src[(xp * NYD + ym) * 9 + 6];
    const float f7 = src[(xp * NYD + yp) * 9 + 7];
    const float f8 = src[(xm * NYD + yp) * 9 + 8];

    float o0,o1,o2,o3,o4,o5,o6,o7,o8;
    collide1(f0,f1,f2,f3,f4,f5,f6,f7,f8,
             wp[0],wp[1],wp[2],wp[3],wp[4],wp[5],wp[6],
             o0,o1,o2,o3,o4,o5,o6,o7,o8);

    float* o = dst + (size_t)(x * NYD + y) * 9;
    o[0]=o0; o[1]=o1; o[2]=o2; o[3]=o3; o[4]=o4; o[5]=o5; o[6]=o6; o[7]=o7; o[8]=o8;
}

extern "C" void kernel_launch(void* const* d_in, const int* in_sizes, int n_in,
                              void* d_out, int out_size, void* d_ws, size_t ws_size,
                              hipStream_t stream) {
    const float* f_in = (const float*)d_in[0];
    const float* w    = (const float*)d_in[1];
    float* out = (float*)d_out;
    float* A   = (float*)d_ws;
    const size_t bufBytes = (size_t)NCELL * 9 * sizeof(float);

    if (ws_size >= 2 * bufBytes) {
        float* B = A + (size_t)NCELL * 9;
        k1_sc   <<<4096, 256, 0, stream>>>(f_in, A, w);
        k_sc    <<<1024, 256, 0, stream>>>(A, B, w);
        k_sc    <<<1024, 256, 0, stream>>>(B, A, w);
        k_sc_aos<<<1024, 256, 0, stream>>>(A, out, w);
    } else {
        // fallback: AoS ping-pong via d_out and mutable d_in (harness restores)
        float* fin_mut = (float*)d_in[0];
        lbm_step_aos<<<4096, 256, 0, stream>>>(f_in, out, w);
        lbm_step_aos<<<4096, 256, 0, stream>>>(out, fin_mut, w);
        lbm_step_aos<<<4096, 256, 0, stream>>>(fin_mut, out, w);
        lbm_step_aos<<<4096, 256, 0, stream>>>(out, fin_mut, w);
        hipMemcpyAsync(d_out, fin_mut, bufBytes, hipMemcpyDeviceToDevice, stream);
    }
}

// Round 7
// 135.915 us; speedup vs baseline: 1.2070x; 1.2070x over previous
//
#include <hip/hip_runtime.h>

// D2Q9 MRT (Gram-Schmidt) LBM on 1024x1024, 4 iterations.
// All-float4, branch-free, push-streaming chain (5 kernels):
//   k1 : S1-push   AoS -> SoA planes   (register transpose + edge exchange)
//   k2 : C1 + S2-push  (SoA -> SoA, own-row aligned f4 reads)
//   k3 : C2 + S3-push
//   k4 : C3 + S4-push
//   k5 : C4 + AoS write (own-cell reads, LDS transpose, coalesced f4 out)
// Push stream: value of plane q at source cell (x,y) goes to (x+ex_q,y+ey_q).
// x-shift = row index on the aligned store; y-shift = one edge float per
// plane exchanged between adjacent threads through padded LDS (2-way, free).
// Every global load/store is an aligned float4. No wrap branches anywhere.

#define NXD 1024
#define NYD 1024
#define NCELL (NXD * NYD)
#define ROWF (NYD * 9)    // floats per AoS row

// TAU=0.6, GX=0 (exact no-op), GY=-1e-4
constexpr float INV_TAU = (float)(1.0 / 0.6);
constexpr float TGY     = (float)(0.6 * -1e-4);   // TAU*GY

__device__ __forceinline__ void collide1(
    float f0, float f1, float f2, float f3, float f4,
    float f5, float f6, float f7, float f8,
    const float (&w)[7],
    float& o0, float& o1, float& o2, float& o3, float& o4,
    float& o5, float& o6, float& o7, float& o8)
{
    const float rho = f0 + f1 + f2 + f3 + f4 + f5 + f6 + f7 + f8;
    const float jx0 = f1 - f3 + f5 - f6 - f7 + f8;
    const float jy0 = f2 - f4 + f5 + f6 - f7 - f8;
    const float vx = jx0 / rho;
    const float vy = jy0 / rho;
    const float uy = vy + TGY * rho;          // ux == vx (GX=0)
    const float jx = rho * vx;
    const float jy = rho * uy;
    const float j2 = jx * jx + jy * jy;

    const float ax = f1 + f2 + f3 + f4;
    const float dg = f5 + f6 + f7 + f8;
    const float m3 = -4.f * f0 - ax + 2.f * dg;
    const float m4 =  4.f * f0 - 2.f * ax + dg;
    const float m5 = -2.f * f1 + 2.f * f3 + f5 - f6 - f7 + f8;
    const float m6 = -2.f * f2 + 2.f * f4 + f5 + f6 - f7 - f8;
    const float m7 = f1 - f2 + f3 - f4;
    const float m8 = f5 - f6 + f7 - f8;

    const float me3 = w[0] * rho + w[1] * j2;
    const float me4 = w[2] * rho - w[3] * j2;
    const float me5 = w[4] * jx;
    const float me6 = w[4] * jy;
    const float me7 = w[5] * (jx * jx - jy * jy);
    const float me8 = w[6] * (jx * jy);

    const float mp1 = jx0 - INV_TAU * (jx0 - jx);
    const float mp2 = jy0 - INV_TAU * (jy0 - jy);
    const float mp3 = m3  - INV_TAU * (m3 - me3);
    const float mp4 = m4  - INV_TAU * (m4 - me4);
    const float mp5 = m5  - INV_TAU * (m5 - me5);
    const float mp6 = m6  - INV_TAU * (m6 - me6);
    const float mp7 = m7  - INV_TAU * (m7 - me7);
    const float mp8 = m8  - INV_TAU * (m8 - me8);

    const float s0 = rho * (1.f / 9.f);
    const float s1 = mp1 * (1.f / 6.f);
    const float s2 = mp2 * (1.f / 6.f);
    const float s3 = mp3 * (1.f / 36.f);
    const float s4 = mp4 * (1.f / 36.f);
    const float s5 = mp5 * (1.f / 12.f);
    const float s6 = mp6 * (1.f / 12.f);
    const float s7 = mp7 * 0.25f;
    const float s8 = mp8 * 0.25f;

    const float h0 = s0 - s3 - 2.f * s4;
    const float g0 = s0 + 2.f * s3 + s4;

    o0 = s0 - 4.f * s3 + 4.f * s4;
    o1 = h0 + s1 - 2.f * s5 + s7;
    o2 = h0 + s2 - 2.f * s6 - s7;
    o3 = h0 - s1 + 2.f * s5 + s7;
    o4 = h0 - s2 + 2.f * s6 - s7;
    o5 = g0 + s1 + s2 + s5 + s6 + s8;
    o6 = g0 - s1 + s2 - s5 + s6 - s8;
    o7 = g0 - s1 - s2 - s5 - s6 + s8;
    o8 = g0 + s1 - s2 + s5 - s6 - s8;
}

// collide 4 cells held as 9 float4 fragments (fully unrolled, stays in regs)
__device__ __forceinline__ void collide4(const float4 (&F)[9], float4 (&O)[9],
                                         const float (&w)[7]) {
    #pragma unroll
    for (int j = 0; j < 4; ++j) {
        float f[9], o[9];
        #pragma unroll
        for (int q = 0; q < 9; ++q)
            f[q] = ((const float*)&F[q])[j];
        collide1(f[0], f[1], f[2], f[3], f[4], f[5], f[6], f[7], f[8], w,
                 o[0], o[1], o[2], o[3], o[4], o[5], o[6], o[7], o[8]);
        #pragma unroll
        for (int q = 0; q < 9; ++q)
            ((float*)&O[q])[j] = o[q];
    }
}

__device__ __forceinline__ void load_w(const float* __restrict__ wp,
                                       float (&w)[7]) {
    #pragma unroll
    for (int i = 0; i < 7; ++i) w[i] = wp[i];
}

// Edge-exchange + push-store the 9 plane fragments P (source cells y0..y0+3
// of row x) into dst planes with streaming shift (+ex row, +ey column).
// E must be __shared__ float [256][7] (pad 7 -> 2-way bank alias, free).
__device__ __forceinline__ void push_store(float* __restrict__ dst,
                                           const float4 (&P)[9],
                                           float (&E)[256][7],
                                           int x, int t) {
    const int y0 = t << 2;
    // ey=+1 planes {2,5,6} need prev thread's .w; ey=-1 planes {4,7,8} next's .x
    E[t][0] = P[2].w;  E[t][1] = P[5].w;  E[t][2] = P[6].w;
    E[t][3] = P[4].x;  E[t][4] = P[7].x;  E[t][5] = P[8].x;
    __syncthreads();
    const int tm = (t - 1) & 255, tp = (t + 1) & 255;
    const float4 S2 = make_float4(E[tm][0], P[2].x, P[2].y, P[2].z);
    const float4 S5 = make_float4(E[tm][1], P[5].x, P[5].y, P[5].z);
    const float4 S6 = make_float4(E[tm][2], P[6].x, P[6].y, P[6].z);
    const float4 S4 = make_float4(P[4].y, P[4].z, P[4].w, E[tp][3]);
    const float4 S7 = make_float4(P[7].y, P[7].z, P[7].w, E[tp][4]);
    const float4 S8 = make_float4(P[8].y, P[8].z, P[8].w, E[tp][5]);
    const int xp = (x + 1) & (NXD - 1), xm = (x - 1) & (NXD - 1);
    *(float4*)(dst + 0 * NCELL + x  * NYD + y0) = P[0];
    *(float4*)(dst + 1 * NCELL + xp * NYD + y0) = P[1];
    *(float4*)(dst + 3 * NCELL + xm * NYD + y0) = P[3];
    *(float4*)(dst + 2 * NCELL + x  * NYD + y0) = S2;
    *(float4*)(dst + 5 * NCELL + xp * NYD + y0) = S5;
    *(float4*)(dst + 6 * NCELL + xm * NYD + y0) = S6;
    *(float4*)(dst + 4 * NCELL + x  * NYD + y0) = S4;
    *(float4*)(dst + 7 * NCELL + xm * NYD + y0) = S7;
    *(float4*)(dst + 8 * NCELL + xp * NYD + y0) = S8;
}

// ---- k1: S1-push, AoS -> SoA. Register transpose of 4 contiguous cells. ----
__global__ __launch_bounds__(256) void k1_push(const float* __restrict__ src,
                                               float* __restrict__ dst) {
    __shared__ float E[256][7];
    const int x = blockIdx.x, t = threadIdx.x;

    float4 A[9];   // 36 contiguous floats = cells y0..y0+3, AoS
    const float* base = src + (size_t)x * ROWF + t * 36;
    #pragma unroll
    for (int q = 0; q < 9; ++q)
        A[q] = *(const float4*)(base + 4 * q);

    const float* a = (const float*)A;   // compile-time indices only
    float4 P[9];
    #pragma unroll
    for (int q = 0; q < 9; ++q)
        P[q] = make_float4(a[q], a[9 + q], a[18 + q], a[27 + q]);

    push_store(dst, P, E, x, t);
}

// ---- k2..k4: C + S-push. Own-row aligned f4 reads from all 9 planes. ----
__global__ __launch_bounds__(256) void k_cs(const float* __restrict__ src,
                                            float* __restrict__ dst,
                                            const float* __restrict__ wp) {
    __shared__ float E[256][7];
    const int x = blockIdx.x, t = threadIdx.x;
    const int y0 = t << 2;

    float4 F[9];
    #pragma unroll
    for (int q = 0; q < 9; ++q)
        F[q] = *(const float4*)(src + q * NCELL + x * NYD + y0);

    float w[7];
    load_w(wp, w);

    float4 O[9];
    collide4(F, O, w);

    push_store(dst, O, E, x, t);
}

// ---- k5: C4 + AoS write. Own-cell reads; LDS transpose; coalesced f4 out. --
__global__ __launch_bounds__(256) void k5_aos(const float* __restrict__ src,
                                              float* __restrict__ dst,
                                              const float* __restrict__ wp) {
    __shared__ float4 T[ROWF / 4];    // one AoS row, 36864 B
    const int x = blockIdx.x, t = threadIdx.x;
    const int y0 = t << 2;

    float4 F[9];
    #pragma unroll
    for (int q = 0; q < 9; ++q)
        F[q] = *(const float4*)(src + q * NCELL + x * NYD + y0);

    float w[7];
    load_w(wp, w);

    float4 O[9];
    collide4(F, O, w);

    float* tt = (float*)(T + t * 9);  // 36 contiguous floats, AoS cell order
    #pragma unroll
    for (int j = 0; j < 4; ++j) {
        #pragma unroll
        for (int q = 0; q < 9; ++q)
            tt[j * 9 + q] = ((const float*)&O[q])[j];
    }
    __syncthreads();

    float4* dv = (float4*)(dst + (size_t)x * ROWF);
    #pragma unroll
    for (int it = 0; it < 9; ++it)
        dv[t + it * 256] = T[t + it * 256];
}

// ---- fallback: plain AoS->AoS fused stream+collide (scalar gather) ----
__global__ __launch_bounds__(256) void lbm_step_aos(const float* __restrict__ src,
                                                    float* __restrict__ dst,
                                                    const float* __restrict__ wp) {
    const int cell = blockIdx.x * 256 + threadIdx.x;
    const int x = cell >> 10;
    const int y = cell & (NYD - 1);
    const int xm = (x + NXD - 1) & (NXD - 1);
    const int xp = (x + 1) & (NXD - 1);
    const int ym = (y + NYD - 1) & (NYD - 1);
    const int yp = (y + 1) & (NYD - 1);

    const float f0 = src[(x  * NYD + y ) * 9 + 0];
    const float f1 = src[(xm * NYD + y ) * 9 + 1];
    const float f2 = src[(x  * NYD + ym) * 9 + 2];
    const float f3 = src[(xp * NYD + y ) * 9 + 3];
    const float f4 = src[(x  * NYD + yp) * 9 + 4];
    const float f5 = src[(xm * NYD + ym) * 9 + 5];
    const float f6 = src[(xp * NYD + ym) * 9 + 6];
    const float f7 = src[(xp * NYD + yp) * 9 + 7];
    const float f8 = src[(xm * NYD + yp) * 9 + 8];

    float w[7];
    load_w(wp, w);
    float o0,o1,o2,o3,o4,o5,o6,o7,o8;
    collide1(f0,f1,f2,f3,f4,f5,f6,f7,f8, w,
             o0,o1,o2,o3,o4,o5,o6,o7,o8);

    float* o = dst + (size_t)(x * NYD + y) * 9;
    o[0]=o0; o[1]=o1; o[2]=o2; o[3]=o3; o[4]=o4; o[5]=o5; o[6]=o6; o[7]=o7; o[8]=o8;
}

extern "C" void kernel_launch(void* const* d_in, const int* in_sizes, int n_in,
                              void* d_out, int out_size, void* d_ws, size_t ws_size,
                              hipStream_t stream) {
    const float* f_in = (const float*)d_in[0];
    const float* w    = (const float*)d_in[1];
    float* out = (float*)d_out;
    float* A   = (float*)d_ws;
    const size_t bufBytes = (size_t)NCELL * 9 * sizeof(float);

    dim3 grid(NXD), block(256);

    if (ws_size >= 2 * bufBytes) {
        float* B = A + (size_t)NCELL * 9;
        k1_push<<<grid, block, 0, stream>>>(f_in, A);        // post-S1
        k_cs   <<<grid, block, 0, stream>>>(A, B, w);        // C1 + S2
        k_cs   <<<grid, block, 0, stream>>>(B, A, w);        // C2 + S3
        k_cs   <<<grid, block, 0, stream>>>(A, B, w);        // C3 + S4
        k5_aos <<<grid, block, 0, stream>>>(B, out, w);      // C4 -> AoS
    } else {
        // fallback: AoS ping-pong via d_out and mutable d_in (harness restores)
        float* fin_mut = (float*)d_in[0];
        lbm_step_aos<<<4096, 256, 0, stream>>>(f_in, out, w);
        lbm_step_aos<<<4096, 256, 0, stream>>>(out, fin_mut, w);
        lbm_step_aos<<<4096, 256, 0, stream>>>(fin_mut, out, w);
        lbm_step_aos<<<4096, 256, 0, stream>>>(out, fin_mut, w);
        hipMemcpyAsync(d_out, fin_mut, bufBytes, hipMemcpyDeviceToDevice, stream);
    }
}